// Round 16
// baseline (215.271 us; speedup 1.0000x reference)
//
#include <hip/hip_runtime.h>
#include <hip/hip_bf16.h>
#include <float.h>
#include <stdint.h>

#define N 8192
#define D 512
#define DZ 64
#define KNN 10
#define REGC 1e-6f
#define KEYBIAS 4096.0f

#define BT 128          // tile rows per side
#define BK 32
#define NBLK (N / BT)   // 64 row-blocks
#define NT (D / BK)     // 16 K-steps

typedef __attribute__((ext_vector_type(8))) short short8v;
typedef __attribute__((ext_vector_type(4))) float f32x4;
typedef __attribute__((ext_vector_type(4))) int int4v;
typedef __attribute__((ext_vector_type(4))) uint uint4v;

#define WAITV0 asm volatile("s_waitcnt vmcnt(0)" ::: "memory")
#define BAR __builtin_amdgcn_s_barrier()

__device__ __forceinline__ void gld16(const ushort* g, ushort* l) {
  __builtin_amdgcn_global_load_lds(
      (const __attribute__((address_space(1))) uint32_t*)g,
      (__attribute__((address_space(3))) uint32_t*)l, 16, 0, 0);
}

__device__ __forceinline__ float b2f(ushort u) {
  return __uint_as_float(((uint)u) << 16);
}

// branchless top-2 (ascending) insert: 3 ops
#define INS2(L0, L1, xv)                 \
  do {                                   \
    const uint _x = (xv);                \
    const uint _lo = _x < L0 ? _x : L0;  \
    const uint _hi = _x < L0 ? L0 : _x;  \
    L0 = _lo;                            \
    L1 = _hi < L1 ? _hi : L1;            \
  } while (0)

// ---------------- kernel 0: sqb = |x|^2 + bias, bf16 copy ----------------
__global__ __launch_bounds__(64) void prep_kernel(const float* __restrict__ X,
                                                  float* __restrict__ sqb,
                                                  ushort* __restrict__ Xb) {
  const int i = blockIdx.x;
  const int lane = threadIdx.x;
  const float4 v0 = *(const float4*)&X[(size_t)i * D + lane * 8];
  const float4 v1 = *(const float4*)&X[(size_t)i * D + lane * 8 + 4];
  float vv[8] = {v0.x, v0.y, v0.z, v0.w, v1.x, v1.y, v1.z, v1.w};
  ushort h[8];
  float s = 0.f;
#pragma unroll
  for (int j = 0; j < 8; ++j) {
    s = fmaf(vv[j], vv[j], s);
    __hip_bfloat16 b = __float2bfloat16(vv[j]);
    h[j] = *(ushort*)&b;
  }
  *(int4v*)&Xb[(size_t)i * D + lane * 8] = *(int4v*)h;
#pragma unroll
  for (int off = 32; off; off >>= 1) s += __shfl_xor(s, off);
  if (lane == 0) sqb[i] = s + KEYBIAS;
}

// ---------------- kernel 1: symmetric tile-pair MFMA + two-sided selection ----------------
// (byte-identical to round 14 except __launch_bounds__(256, 5): 5 blocks/CU.)
__global__ __launch_bounds__(256, 5) void knn_kernel(const ushort* __restrict__ Xb,
                                                     const float* __restrict__ sqb,
                                                     uint* __restrict__ cand) {
  const int bx = blockIdx.x, by = blockIdx.y;
  if (by < bx) return;  // uniform whole-block exit before any barrier

  __shared__ ushort As[2][BT][BK];  // 16 KB
  __shared__ ushort Bs[2][BT][BK];  // 16 KB

  const int i0 = bx * BT;
  const int j0 = by * BT;
  const int tid = threadIdx.x;
  const int lane = tid & 63;
  const int wave = tid >> 6;
  const int wr = wave >> 1, wc = wave & 1;
  const int q = lane >> 4, cr = lane & 15;

  const int srow = tid >> 2, sg = tid & 3;
  const int scsw = (sg ^ ((srow >> 1) & 3)) * 8;
  const size_t aoff0 = (size_t)(i0 + srow) * D + scsw;
  const size_t aoff1 = (size_t)(i0 + 64 + srow) * D + scsw;
  const size_t boff0 = (size_t)(j0 + srow) * D + scsw;
  const size_t boff1 = (size_t)(j0 + 64 + srow) * D + scsw;

  const int fcol = (q ^ ((cr >> 1) & 3)) * 8;

  auto STAGE = [&](int tt) {
    const int bf = tt & 1;
    const int ko = (tt & 15) * BK;
    gld16(Xb + aoff0 + ko, &As[bf][srow][sg * 8]);
    gld16(Xb + aoff1 + ko, &As[bf][64 + srow][sg * 8]);
    gld16(Xb + boff0 + ko, &Bs[bf][srow][sg * 8]);
    gld16(Xb + boff1 + ko, &Bs[bf][64 + srow][sg * 8]);
  };

  f32x4 acc[4][4];  // [n][m]: n = j-group, m = i-group
#pragma unroll
  for (int n = 0; n < 4; ++n)
#pragma unroll
    for (int m = 0; m < 4; ++m) acc[n][m] = (f32x4){0.f, 0.f, 0.f, 0.f};

  STAGE(0);

#pragma unroll 1
  for (int t = 0; t < NT; ++t) {
    const int buf = t & 1;
    WAITV0;
    BAR;
    STAGE((t + 1) & (NT - 1));

    const ushort(*Ab)[BK] = As[buf];
    const ushort(*Bb)[BK] = Bs[buf];
    short8v a[4], b[4];
#pragma unroll
    for (int m = 0; m < 4; ++m)
      a[m] = *(const short8v*)&Ab[wr * 64 + m * 16 + cr][fcol];
#pragma unroll
    for (int n = 0; n < 4; ++n)
      b[n] = *(const short8v*)&Bb[wc * 64 + n * 16 + cr][fcol];
    __builtin_amdgcn_s_setprio(1);
#pragma unroll
    for (int n = 0; n < 4; ++n)
#pragma unroll
      for (int m = 0; m < 4; ++m)
        acc[n][m] = __builtin_amdgcn_mfma_f32_16x16x32_bf16(b[n], a[m], acc[n][m], 0, 0, 0);
    __builtin_amdgcn_s_setprio(0);
  }

  // ---- i-side selection: rows i = i0+wr*64+m*16+cr, cands j in by-block ----
  float sjv[4][4];
#pragma unroll
  for (int n = 0; n < 4; ++n) {
    const float4 tt = *(const float4*)&sqb[j0 + wc * 64 + n * 16 + q * 4];
    sjv[n][0] = tt.x; sjv[n][1] = tt.y; sjv[n][2] = tt.z; sjv[n][3] = tt.w;
  }
#pragma unroll
  for (int m = 0; m < 4; ++m) {
    uint A0 = 0xFFFFFFFFu, A1 = 0xFFFFFFFFu;
#pragma unroll
    for (int n = 0; n < 4; ++n)
#pragma unroll
      for (int s = 0; s < 4; ++s) {
        const float f = fmaf(-2.f, acc[n][m][s], sjv[n][s]);  // > 0 by bias
        const uint pk = (__float_as_uint(f) & 0xFFFFFF80u) |
                        (uint)(wc * 64 + n * 16 + q * 4 + s);
        INS2(A0, A1, pk);
      }
    // exact top-2 of the wave's 64-j band: merge q-lanes (xor16, xor32)
    uint t0 = __shfl_xor(A0, 16), t1 = __shfl_xor(A1, 16);
    INS2(A0, A1, t0); INS2(A0, A1, t1);
    t0 = __shfl_xor(A0, 32); t1 = __shfl_xor(A1, 32);
    INS2(A0, A1, t0); INS2(A0, A1, t1);
    if (q == 0) {
      uint2 v; v.x = A0; v.y = A1;
      *(uint2*)&cand[(size_t)(i0 + wr * 64 + m * 16 + cr) * 256 + by * 4 + wc * 2] = v;
    }
  }

  // ---- j-side selection (off-diag only): rows j, cands i in bx-block ----
  if (bx != by) {
    float siv[4];
#pragma unroll
    for (int m = 0; m < 4; ++m) siv[m] = sqb[i0 + wr * 64 + m * 16 + cr];
#pragma unroll
    for (int n = 0; n < 4; ++n)
#pragma unroll
      for (int s = 0; s < 4; ++s) {
        uint B0 = 0xFFFFFFFFu, B1 = 0xFFFFFFFFu;
#pragma unroll
        for (int m = 0; m < 4; ++m) {
          const float f = fmaf(-2.f, acc[n][m][s], siv[m]);
          const uint pk = (__float_as_uint(f) & 0xFFFFFF80u) |
                          (uint)(wr * 64 + m * 16 + cr);
          INS2(B0, B1, pk);
        }
        // exact top-2 of the wr-half (64 i): merge across cr (xor 1,2,4,8)
#pragma unroll
        for (int off = 1; off <= 8; off <<= 1) {
          const uint u0 = __shfl_xor(B0, off), u1 = __shfl_xor(B1, off);
          INS2(B0, B1, u0); INS2(B0, B1, u1);
        }
        if ((lane & 15) == 0) {
          uint2 v; v.x = B0; v.y = B1;
          *(uint2*)&cand[(size_t)(j0 + wc * 64 + n * 16 + q * 4 + s) * 256 +
                         bx * 4 + wr * 2] = v;
        }
      }
  }
}

// ---------------- kernel 2: direct top-10 merge, bf16 Gram, solve, loss ----------------
__global__ __launch_bounds__(256) void lle_loss_kernel(
    const ushort* __restrict__ Xb, const float* __restrict__ Z,
    const uint* __restrict__ cand, float* __restrict__ rowsse) {
  const int lane = threadIdx.x & 63;
  const int i = blockIdx.x * 4 + (threadIdx.x >> 6);

  // 256 entries = [64 blk][4]; lane's uint4 = blk==lane's 4 entries.
  const uint4v pk4 = *(const uint4v*)&cand[(size_t)i * 256 + lane * 4];
  unsigned long long cvm[4];
#pragma unroll
  for (int kk = 0; kk < 4; ++kk) {
    const int g = lane * BT + (int)(pk4[kk] & 0x7Fu);
    const unsigned long long kv =
        ((unsigned long long)(pk4[kk] >> 7) << 13) | (unsigned long long)g;
    cvm[kk] = (g == i) ? ~0ull : kv;  // self-exclusion
  }

  int nbrj[KNN];
#pragma unroll
  for (int k = 0; k < KNN; ++k) {
    const unsigned long long m01 = cvm[0] < cvm[1] ? cvm[0] : cvm[1];
    const unsigned long long m23 = cvm[2] < cvm[3] ? cvm[2] : cvm[3];
    unsigned long long mn = m01 < m23 ? m01 : m23;
#pragma unroll
    for (int off = 32; off; off >>= 1) {
      const unsigned long long o = __shfl_xor(mn, off);
      mn = o < mn ? o : mn;
    }
    nbrj[k] = (int)(mn & 0x1FFFull);
#pragma unroll
    for (int kk = 0; kk < 4; ++kk)
      cvm[kk] = (cvm[kk] == mn) ? ~0ull : cvm[kk];  // u64 values unique
  }

  float xi[8];
  {
    const short8v v = *(const short8v*)&Xb[(size_t)i * D + lane * 8];
#pragma unroll
    for (int c = 0; c < 8; ++c) xi[c] = b2f((ushort)v[c]);
  }

  float df[KNN][8];
#pragma unroll
  for (int k = 0; k < KNN; ++k) {
    const int j = nbrj[k];
    const short8v v = *(const short8v*)&Xb[(size_t)j * D + lane * 8];
#pragma unroll
    for (int c = 0; c < 8; ++c) df[k][c] = b2f((ushort)v[c]) - xi[c];
  }

  float C[KNN][KNN];
#pragma unroll
  for (int k = 0; k < KNN; ++k) {
#pragma unroll
    for (int l = 0; l <= k; ++l) {
      float p = 0.f;
#pragma unroll
      for (int c = 0; c < 8; ++c) p = fmaf(df[k][c], df[l][c], p);
#pragma unroll
      for (int off = 32; off; off >>= 1) p += __shfl_xor(p, off);
      C[k][l] = p;
    }
  }

  float dinv[KNN];
#pragma unroll
  for (int j = 0; j < KNN; ++j) {
    float s = C[j][j] + REGC;
#pragma unroll
    for (int t = 0; t < KNN; ++t)
      if (t < j) s -= C[j][t] * C[j][t];
    const float dj = sqrtf(s);
    const float inv = 1.f / dj;
    dinv[j] = inv;
#pragma unroll
    for (int r2 = 0; r2 < KNN; ++r2) {
      if (r2 > j) {
        float s2 = C[r2][j];
#pragma unroll
        for (int t = 0; t < KNN; ++t)
          if (t < j) s2 -= C[r2][t] * C[j][t];
        C[r2][j] = s2 * inv;
      }
    }
  }
  float y[KNN], w[KNN];
#pragma unroll
  for (int r2 = 0; r2 < KNN; ++r2) {  // L y = 1
    float s = 1.f;
#pragma unroll
    for (int t = 0; t < KNN; ++t)
      if (t < r2) s -= C[r2][t] * y[t];
    y[r2] = s * dinv[r2];
  }
#pragma unroll
  for (int r2 = KNN - 1; r2 >= 0; --r2) {  // L^T w = y
    float s2 = y[r2];
#pragma unroll
    for (int t = 0; t < KNN; ++t)
      if (t > r2) s2 -= C[t][r2] * w[t];
    w[r2] = s2 * dinv[r2];
  }
  float ws = 0.f;
#pragma unroll
  for (int k = 0; k < KNN; ++k) ws += w[k];
  const float winv = 1.f / ws;

  float zr = 0.f;
#pragma unroll
  for (int k = 0; k < KNN; ++k)
    zr = fmaf(w[k] * winv, Z[(size_t)nbrj[k] * DZ + lane], zr);
  const float e = zr - Z[(size_t)i * DZ + lane];
  float se = e * e;
#pragma unroll
  for (int off = 32; off; off >>= 1) se += __shfl_xor(se, off);
  if (lane == 0) rowsse[i] = se;
}

// ---------------- kernel 3: single-block final reduction ----------------
__global__ __launch_bounds__(256) void reduce_kernel(const float* __restrict__ rowsse,
                                                     float* __restrict__ out) {
  const int tid = threadIdx.x;
  float s = 0.f;
#pragma unroll
  for (int c = 0; c < N / 256; ++c) s += rowsse[c * 256 + tid];
#pragma unroll
  for (int off = 32; off; off >>= 1) s += __shfl_xor(s, off);
  __shared__ float part[4];
  if ((tid & 63) == 0) part[tid >> 6] = s;
  __syncthreads();
  if (tid == 0)
    out[0] = (part[0] + part[1] + part[2] + part[3]) * (1.f / ((float)N * DZ));
}

// ---------------- launch ----------------
extern "C" void kernel_launch(void* const* d_in, const int* in_sizes, int n_in,
                              void* d_out, int out_size, void* d_ws, size_t ws_size,
                              hipStream_t stream) {
  const float* X = (const float*)d_in[0];
  const float* Z = (const float*)d_in[1];
  float* out = (float*)d_out;

  char* ws = (char*)d_ws;
  float* sqb = (float*)ws;                                   // 32 KB
  float* rowsse = (float*)(ws + 32 * 1024);                  // 32 KB
  ushort* Xb = (ushort*)(ws + 64 * 1024);                    // 8 MB
  uint* cand = (uint*)(ws + 64 * 1024 + (size_t)N * D * 2);  // 8 MB

  prep_kernel<<<N, 64, 0, stream>>>(X, sqb, Xb);
  knn_kernel<<<dim3(NBLK, NBLK), 256, 0, stream>>>(Xb, sqb, cand);
  lle_loss_kernel<<<N / 4, 256, 0, stream>>>(Xb, Z, cand, rowsse);
  reduce_kernel<<<1, 256, 0, stream>>>(rowsse, out);
}

// Round 17
// 127.559 us; speedup vs baseline: 1.6876x; 1.6876x over previous
//
#include <hip/hip_runtime.h>
#include <hip/hip_bf16.h>
#include <float.h>
#include <stdint.h>

#define N 8192
#define D 512
#define DZ 64
#define KNN 10
#define REGC 1e-6f
#define KEYBIAS 4096.0f

#define BT 128          // tile rows per side
#define BK 32
#define NBLK (N / BT)   // 64 row-blocks
#define NT (D / BK)     // 16 K-steps

typedef __attribute__((ext_vector_type(8))) short short8v;
typedef __attribute__((ext_vector_type(4))) float f32x4;
typedef __attribute__((ext_vector_type(4))) int int4v;
typedef __attribute__((ext_vector_type(4))) uint uint4v;

#define WAITV0 asm volatile("s_waitcnt vmcnt(0)" ::: "memory")
#define BAR __builtin_amdgcn_s_barrier()

__device__ __forceinline__ void gld16(const ushort* g, ushort* l) {
  __builtin_amdgcn_global_load_lds(
      (const __attribute__((address_space(1))) uint32_t*)g,
      (__attribute__((address_space(3))) uint32_t*)l, 16, 0, 0);
}

__device__ __forceinline__ float b2f(ushort u) {
  return __uint_as_float(((uint)u) << 16);
}

// branchless top-2 (ascending) insert: 3 ops
#define INS2(L0, L1, xv)                 \
  do {                                   \
    const uint _x = (xv);                \
    const uint _lo = _x < L0 ? _x : L0;  \
    const uint _hi = _x < L0 ? L0 : _x;  \
    L0 = _lo;                            \
    L1 = _hi < L1 ? _hi : L1;            \
  } while (0)

// ---------------- kernel 0: sqb = |x|^2 + bias, bf16 copy ----------------
__global__ __launch_bounds__(64) void prep_kernel(const float* __restrict__ X,
                                                  float* __restrict__ sqb,
                                                  ushort* __restrict__ Xb) {
  const int i = blockIdx.x;
  const int lane = threadIdx.x;
  const float4 v0 = *(const float4*)&X[(size_t)i * D + lane * 8];
  const float4 v1 = *(const float4*)&X[(size_t)i * D + lane * 8 + 4];
  float vv[8] = {v0.x, v0.y, v0.z, v0.w, v1.x, v1.y, v1.z, v1.w};
  ushort h[8];
  float s = 0.f;
#pragma unroll
  for (int j = 0; j < 8; ++j) {
    s = fmaf(vv[j], vv[j], s);
    __hip_bfloat16 b = __float2bfloat16(vv[j]);
    h[j] = *(ushort*)&b;
  }
  *(int4v*)&Xb[(size_t)i * D + lane * 8] = *(int4v*)h;
#pragma unroll
  for (int off = 32; off; off >>= 1) s += __shfl_xor(s, off);
  if (lane == 0) sqb[i] = s + KEYBIAS;
}

// ---------------- kernel 1: symmetric tile-pair MFMA + two-sided selection ----------------
// (byte-identical to round 14: __launch_bounds__(256, 4), 2-buffer pipeline.)
__global__ __launch_bounds__(256, 4) void knn_kernel(const ushort* __restrict__ Xb,
                                                     const float* __restrict__ sqb,
                                                     uint* __restrict__ cand) {
  const int bx = blockIdx.x, by = blockIdx.y;
  if (by < bx) return;  // uniform whole-block exit before any barrier

  __shared__ ushort As[2][BT][BK];  // 16 KB
  __shared__ ushort Bs[2][BT][BK];  // 16 KB

  const int i0 = bx * BT;
  const int j0 = by * BT;
  const int tid = threadIdx.x;
  const int lane = tid & 63;
  const int wave = tid >> 6;
  const int wr = wave >> 1, wc = wave & 1;
  const int q = lane >> 4, cr = lane & 15;

  const int srow = tid >> 2, sg = tid & 3;
  const int scsw = (sg ^ ((srow >> 1) & 3)) * 8;
  const size_t aoff0 = (size_t)(i0 + srow) * D + scsw;
  const size_t aoff1 = (size_t)(i0 + 64 + srow) * D + scsw;
  const size_t boff0 = (size_t)(j0 + srow) * D + scsw;
  const size_t boff1 = (size_t)(j0 + 64 + srow) * D + scsw;

  const int fcol = (q ^ ((cr >> 1) & 3)) * 8;

  auto STAGE = [&](int tt) {
    const int bf = tt & 1;
    const int ko = (tt & 15) * BK;
    gld16(Xb + aoff0 + ko, &As[bf][srow][sg * 8]);
    gld16(Xb + aoff1 + ko, &As[bf][64 + srow][sg * 8]);
    gld16(Xb + boff0 + ko, &Bs[bf][srow][sg * 8]);
    gld16(Xb + boff1 + ko, &Bs[bf][64 + srow][sg * 8]);
  };

  f32x4 acc[4][4];  // [n][m]: n = j-group, m = i-group
#pragma unroll
  for (int n = 0; n < 4; ++n)
#pragma unroll
    for (int m = 0; m < 4; ++m) acc[n][m] = (f32x4){0.f, 0.f, 0.f, 0.f};

  STAGE(0);

#pragma unroll 1
  for (int t = 0; t < NT; ++t) {
    const int buf = t & 1;
    WAITV0;
    BAR;
    STAGE((t + 1) & (NT - 1));

    const ushort(*Ab)[BK] = As[buf];
    const ushort(*Bb)[BK] = Bs[buf];
    short8v a[4], b[4];
#pragma unroll
    for (int m = 0; m < 4; ++m)
      a[m] = *(const short8v*)&Ab[wr * 64 + m * 16 + cr][fcol];
#pragma unroll
    for (int n = 0; n < 4; ++n)
      b[n] = *(const short8v*)&Bb[wc * 64 + n * 16 + cr][fcol];
    __builtin_amdgcn_s_setprio(1);
#pragma unroll
    for (int n = 0; n < 4; ++n)
#pragma unroll
      for (int m = 0; m < 4; ++m)
        acc[n][m] = __builtin_amdgcn_mfma_f32_16x16x32_bf16(b[n], a[m], acc[n][m], 0, 0, 0);
    __builtin_amdgcn_s_setprio(0);
  }

  // ---- i-side selection: rows i = i0+wr*64+m*16+cr, cands j in by-block ----
  float sjv[4][4];
#pragma unroll
  for (int n = 0; n < 4; ++n) {
    const float4 tt = *(const float4*)&sqb[j0 + wc * 64 + n * 16 + q * 4];
    sjv[n][0] = tt.x; sjv[n][1] = tt.y; sjv[n][2] = tt.z; sjv[n][3] = tt.w;
  }
#pragma unroll
  for (int m = 0; m < 4; ++m) {
    uint A0 = 0xFFFFFFFFu, A1 = 0xFFFFFFFFu;
#pragma unroll
    for (int n = 0; n < 4; ++n)
#pragma unroll
      for (int s = 0; s < 4; ++s) {
        const float f = fmaf(-2.f, acc[n][m][s], sjv[n][s]);  // > 0 by bias
        const uint pk = (__float_as_uint(f) & 0xFFFFFF80u) |
                        (uint)(wc * 64 + n * 16 + q * 4 + s);
        INS2(A0, A1, pk);
      }
    // exact top-2 of the wave's 64-j band: merge q-lanes (xor16, xor32)
    uint t0 = __shfl_xor(A0, 16), t1 = __shfl_xor(A1, 16);
    INS2(A0, A1, t0); INS2(A0, A1, t1);
    t0 = __shfl_xor(A0, 32); t1 = __shfl_xor(A1, 32);
    INS2(A0, A1, t0); INS2(A0, A1, t1);
    if (q == 0) {
      uint2 v; v.x = A0; v.y = A1;
      *(uint2*)&cand[(size_t)(i0 + wr * 64 + m * 16 + cr) * 256 + by * 4 + wc * 2] = v;
    }
  }

  // ---- j-side selection (off-diag only): rows j, cands i in bx-block ----
  if (bx != by) {
    float siv[4];
#pragma unroll
    for (int m = 0; m < 4; ++m) siv[m] = sqb[i0 + wr * 64 + m * 16 + cr];
#pragma unroll
    for (int n = 0; n < 4; ++n)
#pragma unroll
      for (int s = 0; s < 4; ++s) {
        uint B0 = 0xFFFFFFFFu, B1 = 0xFFFFFFFFu;
#pragma unroll
        for (int m = 0; m < 4; ++m) {
          const float f = fmaf(-2.f, acc[n][m][s], siv[m]);
          const uint pk = (__float_as_uint(f) & 0xFFFFFF80u) |
                          (uint)(wr * 64 + m * 16 + cr);
          INS2(B0, B1, pk);
        }
        // exact top-2 of the wr-half (64 i): merge across cr (xor 1,2,4,8)
#pragma unroll
        for (int off = 1; off <= 8; off <<= 1) {
          const uint u0 = __shfl_xor(B0, off), u1 = __shfl_xor(B1, off);
          INS2(B0, B1, u0); INS2(B0, B1, u1);
        }
        if ((lane & 15) == 0) {
          uint2 v; v.x = B0; v.y = B1;
          *(uint2*)&cand[(size_t)(j0 + wc * 64 + n * 16 + q * 4 + s) * 256 +
                         bx * 4 + wr * 2] = v;
        }
      }
  }
}

// ---------------- kernel 2: direct top-10 merge, bf16 Gram, solve, loss ----------------
__global__ __launch_bounds__(256) void lle_loss_kernel(
    const ushort* __restrict__ Xb, const float* __restrict__ Z,
    const uint* __restrict__ cand, float* __restrict__ rowsse) {
  const int lane = threadIdx.x & 63;
  const int i = blockIdx.x * 4 + (threadIdx.x >> 6);

  // 256 entries = [64 blk][4]; lane's uint4 = blk==lane's 4 entries.
  const uint4v pk4 = *(const uint4v*)&cand[(size_t)i * 256 + lane * 4];
  unsigned long long cvm[4];
#pragma unroll
  for (int kk = 0; kk < 4; ++kk) {
    const int g = lane * BT + (int)(pk4[kk] & 0x7Fu);
    const unsigned long long kv =
        ((unsigned long long)(pk4[kk] >> 7) << 13) | (unsigned long long)g;
    cvm[kk] = (g == i) ? ~0ull : kv;  // self-exclusion
  }

  int nbrj[KNN];
#pragma unroll
  for (int k = 0; k < KNN; ++k) {
    const unsigned long long m01 = cvm[0] < cvm[1] ? cvm[0] : cvm[1];
    const unsigned long long m23 = cvm[2] < cvm[3] ? cvm[2] : cvm[3];
    unsigned long long mn = m01 < m23 ? m01 : m23;
#pragma unroll
    for (int off = 32; off; off >>= 1) {
      const unsigned long long o = __shfl_xor(mn, off);
      mn = o < mn ? o : mn;
    }
    nbrj[k] = (int)(mn & 0x1FFFull);
#pragma unroll
    for (int kk = 0; kk < 4; ++kk)
      cvm[kk] = (cvm[kk] == mn) ? ~0ull : cvm[kk];  // u64 values unique
  }

  float xi[8];
  {
    const short8v v = *(const short8v*)&Xb[(size_t)i * D + lane * 8];
#pragma unroll
    for (int c = 0; c < 8; ++c) xi[c] = b2f((ushort)v[c]);
  }

  float df[KNN][8];
#pragma unroll
  for (int k = 0; k < KNN; ++k) {
    const int j = nbrj[k];
    const short8v v = *(const short8v*)&Xb[(size_t)j * D + lane * 8];
#pragma unroll
    for (int c = 0; c < 8; ++c) df[k][c] = b2f((ushort)v[c]) - xi[c];
  }

  float C[KNN][KNN];
#pragma unroll
  for (int k = 0; k < KNN; ++k) {
#pragma unroll
    for (int l = 0; l <= k; ++l) {
      float p = 0.f;
#pragma unroll
      for (int c = 0; c < 8; ++c) p = fmaf(df[k][c], df[l][c], p);
#pragma unroll
      for (int off = 32; off; off >>= 1) p += __shfl_xor(p, off);
      C[k][l] = p;
    }
  }

  float dinv[KNN];
#pragma unroll
  for (int j = 0; j < KNN; ++j) {
    float s = C[j][j] + REGC;
#pragma unroll
    for (int t = 0; t < KNN; ++t)
      if (t < j) s -= C[j][t] * C[j][t];
    const float dj = sqrtf(s);
    const float inv = 1.f / dj;
    dinv[j] = inv;
#pragma unroll
    for (int r2 = 0; r2 < KNN; ++r2) {
      if (r2 > j) {
        float s2 = C[r2][j];
#pragma unroll
        for (int t = 0; t < KNN; ++t)
          if (t < j) s2 -= C[r2][t] * C[j][t];
        C[r2][j] = s2 * inv;
      }
    }
  }
  float y[KNN], w[KNN];
#pragma unroll
  for (int r2 = 0; r2 < KNN; ++r2) {  // L y = 1
    float s = 1.f;
#pragma unroll
    for (int t = 0; t < KNN; ++t)
      if (t < r2) s -= C[r2][t] * y[t];
    y[r2] = s * dinv[r2];
  }
#pragma unroll
  for (int r2 = KNN - 1; r2 >= 0; --r2) {  // L^T w = y
    float s2 = y[r2];
#pragma unroll
    for (int t = 0; t < KNN; ++t)
      if (t > r2) s2 -= C[t][r2] * w[t];
    w[r2] = s2 * dinv[r2];
  }
  float ws = 0.f;
#pragma unroll
  for (int k = 0; k < KNN; ++k) ws += w[k];
  const float winv = 1.f / ws;

  float zr = 0.f;
#pragma unroll
  for (int k = 0; k < KNN; ++k)
    zr = fmaf(w[k] * winv, Z[(size_t)nbrj[k] * DZ + lane], zr);
  const float e = zr - Z[(size_t)i * DZ + lane];
  float se = e * e;
#pragma unroll
  for (int off = 32; off; off >>= 1) se += __shfl_xor(se, off);
  if (lane == 0) rowsse[i] = se;
}

// ---------------- kernel 3: single-block final reduction ----------------
__global__ __launch_bounds__(256) void reduce_kernel(const float* __restrict__ rowsse,
                                                     float* __restrict__ out) {
  const int tid = threadIdx.x;
  float s = 0.f;
#pragma unroll
  for (int c = 0; c < N / 256; ++c) s += rowsse[c * 256 + tid];
#pragma unroll
  for (int off = 32; off; off >>= 1) s += __shfl_xor(s, off);
  __shared__ float part[4];
  if ((tid & 63) == 0) part[tid >> 6] = s;
  __syncthreads();
  if (tid == 0)
    out[0] = (part[0] + part[1] + part[2] + part[3]) * (1.f / ((float)N * DZ));
}

// ---------------- launch ----------------
extern "C" void kernel_launch(void* const* d_in, const int* in_sizes, int n_in,
                              void* d_out, int out_size, void* d_ws, size_t ws_size,
                              hipStream_t stream) {
  const float* X = (const float*)d_in[0];
  const float* Z = (const float*)d_in[1];
  float* out = (float*)d_out;

  char* ws = (char*)d_ws;
  float* sqb = (float*)ws;                                   // 32 KB
  float* rowsse = (float*)(ws + 32 * 1024);                  // 32 KB
  ushort* Xb = (ushort*)(ws + 64 * 1024);                    // 8 MB
  uint* cand = (uint*)(ws + 64 * 1024 + (size_t)N * D * 2);  // 8 MB

  prep_kernel<<<N, 64, 0, stream>>>(X, sqb, Xb);
  knn_kernel<<<dim3(NBLK, NBLK), 256, 0, stream>>>(Xb, sqb, cand);
  lle_loss_kernel<<<N / 4, 256, 0, stream>>>(Xb, Z, cand, rowsse);
  reduce_kernel<<<1, 256, 0, stream>>>(rowsse, out);
}

// Round 18
// 119.391 us; speedup vs baseline: 1.8031x; 1.0684x over previous
//
#include <hip/hip_runtime.h>
#include <hip/hip_bf16.h>
#include <float.h>
#include <stdint.h>
#include <math.h>

#define N 8192
#define D 512
#define DZ 64
#define KNN 10
#define REGC 1e-6f
#define KEYBIAS 4096.0f

#define BT 128          // tile rows per side
#define BK 32
#define NBLK (N / BT)   // 64 row-blocks
#define NT (D / BK)     // 16 K-steps
#define NPAIR (NBLK * (NBLK + 1) / 2)  // 2080 upper-triangle tile pairs
#define NXCD 8
#define CPX (NPAIR / NXCD)             // 260 pairs per XCD chunk

typedef __attribute__((ext_vector_type(8))) short short8v;
typedef __attribute__((ext_vector_type(4))) float f32x4;
typedef __attribute__((ext_vector_type(4))) int int4v;
typedef __attribute__((ext_vector_type(4))) uint uint4v;

#define WAITV0 asm volatile("s_waitcnt vmcnt(0)" ::: "memory")
#define BAR __builtin_amdgcn_s_barrier()

__device__ __forceinline__ void gld16(const ushort* g, ushort* l) {
  __builtin_amdgcn_global_load_lds(
      (const __attribute__((address_space(1))) uint32_t*)g,
      (__attribute__((address_space(3))) uint32_t*)l, 16, 0, 0);
}

__device__ __forceinline__ float b2f(ushort u) {
  return __uint_as_float(((uint)u) << 16);
}

// branchless top-2 (ascending) insert: 3 ops
#define INS2(L0, L1, xv)                 \
  do {                                   \
    const uint _x = (xv);                \
    const uint _lo = _x < L0 ? _x : L0;  \
    const uint _hi = _x < L0 ? L0 : _x;  \
    L0 = _lo;                            \
    L1 = _hi < L1 ? _hi : L1;            \
  } while (0)

// ---------------- kernel 0: sqb = |x|^2 + bias, bf16 copy ----------------
__global__ __launch_bounds__(64) void prep_kernel(const float* __restrict__ X,
                                                  float* __restrict__ sqb,
                                                  ushort* __restrict__ Xb) {
  const int i = blockIdx.x;
  const int lane = threadIdx.x;
  const float4 v0 = *(const float4*)&X[(size_t)i * D + lane * 8];
  const float4 v1 = *(const float4*)&X[(size_t)i * D + lane * 8 + 4];
  float vv[8] = {v0.x, v0.y, v0.z, v0.w, v1.x, v1.y, v1.z, v1.w};
  ushort h[8];
  float s = 0.f;
#pragma unroll
  for (int j = 0; j < 8; ++j) {
    s = fmaf(vv[j], vv[j], s);
    __hip_bfloat16 b = __float2bfloat16(vv[j]);
    h[j] = *(ushort*)&b;
  }
  *(int4v*)&Xb[(size_t)i * D + lane * 8] = *(int4v*)h;
#pragma unroll
  for (int off = 32; off; off >>= 1) s += __shfl_xor(s, off);
  if (lane == 0) sqb[i] = s + KEYBIAS;
}

// ---------------- kernel 1: symmetric tile-pair MFMA + two-sided selection ----------------
// Body byte-identical to round 17; only the (bx,by) derivation changed:
// 1D grid of exactly NPAIR blocks, XCD-chunk swizzle W = (p%8)*260 + p/8
// (bijective; each XCD gets a contiguous triangle chunk -> B-tiles ~47x
// L2 reuse within an XCD instead of ~6x), then triangular decode W->(by,bx).
__global__ __launch_bounds__(256, 4) void knn_kernel(const ushort* __restrict__ Xb,
                                                     const float* __restrict__ sqb,
                                                     uint* __restrict__ cand) {
  const int p = blockIdx.x;
  const int W = (p & 7) * CPX + (p >> 3);  // 2080 % 8 == 0 -> bijective
  int by = (int)((sqrt(8.0 * W + 1.0) - 1.0) * 0.5);
  while ((by + 1) * (by + 2) / 2 <= W) ++by;  // exact correction
  while (by * (by + 1) / 2 > W) --by;
  const int bx = W - by * (by + 1) / 2;  // bx <= by by construction

  __shared__ ushort As[2][BT][BK];  // 16 KB
  __shared__ ushort Bs[2][BT][BK];  // 16 KB

  const int i0 = bx * BT;
  const int j0 = by * BT;
  const int tid = threadIdx.x;
  const int lane = tid & 63;
  const int wave = tid >> 6;
  const int wr = wave >> 1, wc = wave & 1;
  const int q = lane >> 4, cr = lane & 15;

  const int srow = tid >> 2, sg = tid & 3;
  const int scsw = (sg ^ ((srow >> 1) & 3)) * 8;
  const size_t aoff0 = (size_t)(i0 + srow) * D + scsw;
  const size_t aoff1 = (size_t)(i0 + 64 + srow) * D + scsw;
  const size_t boff0 = (size_t)(j0 + srow) * D + scsw;
  const size_t boff1 = (size_t)(j0 + 64 + srow) * D + scsw;

  const int fcol = (q ^ ((cr >> 1) & 3)) * 8;

  auto STAGE = [&](int tt) {
    const int bf = tt & 1;
    const int ko = (tt & 15) * BK;
    gld16(Xb + aoff0 + ko, &As[bf][srow][sg * 8]);
    gld16(Xb + aoff1 + ko, &As[bf][64 + srow][sg * 8]);
    gld16(Xb + boff0 + ko, &Bs[bf][srow][sg * 8]);
    gld16(Xb + boff1 + ko, &Bs[bf][64 + srow][sg * 8]);
  };

  f32x4 acc[4][4];  // [n][m]: n = j-group, m = i-group
#pragma unroll
  for (int n = 0; n < 4; ++n)
#pragma unroll
    for (int m = 0; m < 4; ++m) acc[n][m] = (f32x4){0.f, 0.f, 0.f, 0.f};

  STAGE(0);

#pragma unroll 1
  for (int t = 0; t < NT; ++t) {
    const int buf = t & 1;
    WAITV0;
    BAR;
    STAGE((t + 1) & (NT - 1));

    const ushort(*Ab)[BK] = As[buf];
    const ushort(*Bb)[BK] = Bs[buf];
    short8v a[4], b[4];
#pragma unroll
    for (int m = 0; m < 4; ++m)
      a[m] = *(const short8v*)&Ab[wr * 64 + m * 16 + cr][fcol];
#pragma unroll
    for (int n = 0; n < 4; ++n)
      b[n] = *(const short8v*)&Bb[wc * 64 + n * 16 + cr][fcol];
    __builtin_amdgcn_s_setprio(1);
#pragma unroll
    for (int n = 0; n < 4; ++n)
#pragma unroll
      for (int m = 0; m < 4; ++m)
        acc[n][m] = __builtin_amdgcn_mfma_f32_16x16x32_bf16(b[n], a[m], acc[n][m], 0, 0, 0);
    __builtin_amdgcn_s_setprio(0);
  }

  // ---- i-side selection: rows i = i0+wr*64+m*16+cr, cands j in by-block ----
  float sjv[4][4];
#pragma unroll
  for (int n = 0; n < 4; ++n) {
    const float4 tt = *(const float4*)&sqb[j0 + wc * 64 + n * 16 + q * 4];
    sjv[n][0] = tt.x; sjv[n][1] = tt.y; sjv[n][2] = tt.z; sjv[n][3] = tt.w;
  }
#pragma unroll
  for (int m = 0; m < 4; ++m) {
    uint A0 = 0xFFFFFFFFu, A1 = 0xFFFFFFFFu;
#pragma unroll
    for (int n = 0; n < 4; ++n)
#pragma unroll
      for (int s = 0; s < 4; ++s) {
        const float f = fmaf(-2.f, acc[n][m][s], sjv[n][s]);  // > 0 by bias
        const uint pk = (__float_as_uint(f) & 0xFFFFFF80u) |
                        (uint)(wc * 64 + n * 16 + q * 4 + s);
        INS2(A0, A1, pk);
      }
    // exact top-2 of the wave's 64-j band: merge q-lanes (xor16, xor32)
    uint t0 = __shfl_xor(A0, 16), t1 = __shfl_xor(A1, 16);
    INS2(A0, A1, t0); INS2(A0, A1, t1);
    t0 = __shfl_xor(A0, 32); t1 = __shfl_xor(A1, 32);
    INS2(A0, A1, t0); INS2(A0, A1, t1);
    if (q == 0) {
      uint2 v; v.x = A0; v.y = A1;
      *(uint2*)&cand[(size_t)(i0 + wr * 64 + m * 16 + cr) * 256 + by * 4 + wc * 2] = v;
    }
  }

  // ---- j-side selection (off-diag only): rows j, cands i in bx-block ----
  if (bx != by) {
    float siv[4];
#pragma unroll
    for (int m = 0; m < 4; ++m) siv[m] = sqb[i0 + wr * 64 + m * 16 + cr];
#pragma unroll
    for (int n = 0; n < 4; ++n)
#pragma unroll
      for (int s = 0; s < 4; ++s) {
        uint B0 = 0xFFFFFFFFu, B1 = 0xFFFFFFFFu;
#pragma unroll
        for (int m = 0; m < 4; ++m) {
          const float f = fmaf(-2.f, acc[n][m][s], siv[m]);
          const uint pk = (__float_as_uint(f) & 0xFFFFFF80u) |
                          (uint)(wr * 64 + m * 16 + cr);
          INS2(B0, B1, pk);
        }
        // exact top-2 of the wr-half (64 i): merge across cr (xor 1,2,4,8)
#pragma unroll
        for (int off = 1; off <= 8; off <<= 1) {
          const uint u0 = __shfl_xor(B0, off), u1 = __shfl_xor(B1, off);
          INS2(B0, B1, u0); INS2(B0, B1, u1);
        }
        if ((lane & 15) == 0) {
          uint2 v; v.x = B0; v.y = B1;
          *(uint2*)&cand[(size_t)(j0 + wc * 64 + n * 16 + q * 4 + s) * 256 +
                         bx * 4 + wr * 2] = v;
        }
      }
  }
}

// ---------------- kernel 2: direct top-10 merge, bf16 Gram, solve, loss ----------------
__global__ __launch_bounds__(256) void lle_loss_kernel(
    const ushort* __restrict__ Xb, const float* __restrict__ Z,
    const uint* __restrict__ cand, float* __restrict__ rowsse) {
  const int lane = threadIdx.x & 63;
  const int i = blockIdx.x * 4 + (threadIdx.x >> 6);

  // 256 entries = [64 blk][4]; lane's uint4 = blk==lane's 4 entries.
  const uint4v pk4 = *(const uint4v*)&cand[(size_t)i * 256 + lane * 4];
  unsigned long long cvm[4];
#pragma unroll
  for (int kk = 0; kk < 4; ++kk) {
    const int g = lane * BT + (int)(pk4[kk] & 0x7Fu);
    const unsigned long long kv =
        ((unsigned long long)(pk4[kk] >> 7) << 13) | (unsigned long long)g;
    cvm[kk] = (g == i) ? ~0ull : kv;  // self-exclusion
  }

  int nbrj[KNN];
#pragma unroll
  for (int k = 0; k < KNN; ++k) {
    const unsigned long long m01 = cvm[0] < cvm[1] ? cvm[0] : cvm[1];
    const unsigned long long m23 = cvm[2] < cvm[3] ? cvm[2] : cvm[3];
    unsigned long long mn = m01 < m23 ? m01 : m23;
#pragma unroll
    for (int off = 32; off; off >>= 1) {
      const unsigned long long o = __shfl_xor(mn, off);
      mn = o < mn ? o : mn;
    }
    nbrj[k] = (int)(mn & 0x1FFFull);
#pragma unroll
    for (int kk = 0; kk < 4; ++kk)
      cvm[kk] = (cvm[kk] == mn) ? ~0ull : cvm[kk];  // u64 values unique
  }

  float xi[8];
  {
    const short8v v = *(const short8v*)&Xb[(size_t)i * D + lane * 8];
#pragma unroll
    for (int c = 0; c < 8; ++c) xi[c] = b2f((ushort)v[c]);
  }

  float df[KNN][8];
#pragma unroll
  for (int k = 0; k < KNN; ++k) {
    const int j = nbrj[k];
    const short8v v = *(const short8v*)&Xb[(size_t)j * D + lane * 8];
#pragma unroll
    for (int c = 0; c < 8; ++c) df[k][c] = b2f((ushort)v[c]) - xi[c];
  }

  float C[KNN][KNN];
#pragma unroll
  for (int k = 0; k < KNN; ++k) {
#pragma unroll
    for (int l = 0; l <= k; ++l) {
      float p = 0.f;
#pragma unroll
      for (int c = 0; c < 8; ++c) p = fmaf(df[k][c], df[l][c], p);
#pragma unroll
      for (int off = 32; off; off >>= 1) p += __shfl_xor(p, off);
      C[k][l] = p;
    }
  }

  float dinv[KNN];
#pragma unroll
  for (int j = 0; j < KNN; ++j) {
    float s = C[j][j] + REGC;
#pragma unroll
    for (int t = 0; t < KNN; ++t)
      if (t < j) s -= C[j][t] * C[j][t];
    const float dj = sqrtf(s);
    const float inv = 1.f / dj;
    dinv[j] = inv;
#pragma unroll
    for (int r2 = 0; r2 < KNN; ++r2) {
      if (r2 > j) {
        float s2 = C[r2][j];
#pragma unroll
        for (int t = 0; t < KNN; ++t)
          if (t < j) s2 -= C[r2][t] * C[j][t];
        C[r2][j] = s2 * inv;
      }
    }
  }
  float y[KNN], w[KNN];
#pragma unroll
  for (int r2 = 0; r2 < KNN; ++r2) {  // L y = 1
    float s = 1.f;
#pragma unroll
    for (int t = 0; t < KNN; ++t)
      if (t < r2) s -= C[r2][t] * y[t];
    y[r2] = s * dinv[r2];
  }
#pragma unroll
  for (int r2 = KNN - 1; r2 >= 0; --r2) {  // L^T w = y
    float s2 = y[r2];
#pragma unroll
    for (int t = 0; t < KNN; ++t)
      if (t > r2) s2 -= C[t][r2] * w[t];
    w[r2] = s2 * dinv[r2];
  }
  float ws = 0.f;
#pragma unroll
  for (int k = 0; k < KNN; ++k) ws += w[k];
  const float winv = 1.f / ws;

  float zr = 0.f;
#pragma unroll
  for (int k = 0; k < KNN; ++k)
    zr = fmaf(w[k] * winv, Z[(size_t)nbrj[k] * DZ + lane], zr);
  const float e = zr - Z[(size_t)i * DZ + lane];
  float se = e * e;
#pragma unroll
  for (int off = 32; off; off >>= 1) se += __shfl_xor(se, off);
  if (lane == 0) rowsse[i] = se;
}

// ---------------- kernel 3: single-block final reduction ----------------
__global__ __launch_bounds__(256) void reduce_kernel(const float* __restrict__ rowsse,
                                                     float* __restrict__ out) {
  const int tid = threadIdx.x;
  float s = 0.f;
#pragma unroll
  for (int c = 0; c < N / 256; ++c) s += rowsse[c * 256 + tid];
#pragma unroll
  for (int off = 32; off; off >>= 1) s += __shfl_xor(s, off);
  __shared__ float part[4];
  if ((tid & 63) == 0) part[tid >> 6] = s;
  __syncthreads();
  if (tid == 0)
    out[0] = (part[0] + part[1] + part[2] + part[3]) * (1.f / ((float)N * DZ));
}

// ---------------- launch ----------------
extern "C" void kernel_launch(void* const* d_in, const int* in_sizes, int n_in,
                              void* d_out, int out_size, void* d_ws, size_t ws_size,
                              hipStream_t stream) {
  const float* X = (const float*)d_in[0];
  const float* Z = (const float*)d_in[1];
  float* out = (float*)d_out;

  char* ws = (char*)d_ws;
  float* sqb = (float*)ws;                                   // 32 KB
  float* rowsse = (float*)(ws + 32 * 1024);                  // 32 KB
  ushort* Xb = (ushort*)(ws + 64 * 1024);                    // 8 MB
  uint* cand = (uint*)(ws + 64 * 1024 + (size_t)N * D * 2);  // 8 MB

  prep_kernel<<<N, 64, 0, stream>>>(X, sqb, Xb);
  knn_kernel<<<NPAIR, 256, 0, stream>>>(Xb, sqb, cand);
  lle_loss_kernel<<<N / 4, 256, 0, stream>>>(Xb, Z, cand, rowsse);
  reduce_kernel<<<1, 256, 0, stream>>>(rowsse, out);
}

// Round 19
// 117.153 us; speedup vs baseline: 1.8375x; 1.0191x over previous
//
#include <hip/hip_runtime.h>
#include <hip/hip_bf16.h>
#include <float.h>
#include <stdint.h>

#define N 8192
#define D 512
#define DZ 64
#define KNN 10
#define REGC 1e-6f
#define KEYBIAS 4096.0f

#define BT 128          // tile rows per side
#define BK 32
#define NBLK (N / BT)   // 64 row-blocks
#define NT (D / BK)     // 16 K-steps
#define NPAIR (NBLK * (NBLK + 1) / 2)  // 2080 upper-triangle tile pairs
#define NXCD 8
#define CPX (NPAIR / NXCD)             // 260 pairs per XCD chunk

typedef __attribute__((ext_vector_type(8))) short short8v;
typedef __attribute__((ext_vector_type(4))) float f32x4;
typedef __attribute__((ext_vector_type(4))) int int4v;
typedef __attribute__((ext_vector_type(4))) uint uint4v;

#define WAITV0 asm volatile("s_waitcnt vmcnt(0)" ::: "memory")
#define BAR __builtin_amdgcn_s_barrier()

__device__ __forceinline__ void gld16(const ushort* g, ushort* l) {
  __builtin_amdgcn_global_load_lds(
      (const __attribute__((address_space(1))) uint32_t*)g,
      (__attribute__((address_space(3))) uint32_t*)l, 16, 0, 0);
}

__device__ __forceinline__ float b2f(ushort u) {
  return __uint_as_float(((uint)u) << 16);
}

// branchless top-2 (ascending) insert: 3 ops
#define INS2(L0, L1, xv)                 \
  do {                                   \
    const uint _x = (xv);                \
    const uint _lo = _x < L0 ? _x : L0;  \
    const uint _hi = _x < L0 ? L0 : _x;  \
    L0 = _lo;                            \
    L1 = _hi < L1 ? _hi : L1;            \
  } while (0)

// ---------------- kernel 0: sqb = |x|^2 + bias, bf16 copy ----------------
__global__ __launch_bounds__(64) void prep_kernel(const float* __restrict__ X,
                                                  float* __restrict__ sqb,
                                                  ushort* __restrict__ Xb) {
  const int i = blockIdx.x;
  const int lane = threadIdx.x;
  const float4 v0 = *(const float4*)&X[(size_t)i * D + lane * 8];
  const float4 v1 = *(const float4*)&X[(size_t)i * D + lane * 8 + 4];
  float vv[8] = {v0.x, v0.y, v0.z, v0.w, v1.x, v1.y, v1.z, v1.w};
  ushort h[8];
  float s = 0.f;
#pragma unroll
  for (int j = 0; j < 8; ++j) {
    s = fmaf(vv[j], vv[j], s);
    __hip_bfloat16 b = __float2bfloat16(vv[j]);
    h[j] = *(ushort*)&b;
  }
  *(int4v*)&Xb[(size_t)i * D + lane * 8] = *(int4v*)h;
#pragma unroll
  for (int off = 32; off; off >>= 1) s += __shfl_xor(s, off);
  if (lane == 0) sqb[i] = s + KEYBIAS;
}

// ---------------- kernel 1: symmetric tile-pair MFMA + two-sided selection ----------------
// Body byte-identical to round 18; only the W->(bx,by) decode changed to a
// GROUP-PAIR order: 8 groups of 8 tile-rows; pairs enumerated super-row-major
// (per sr: off-diag group-pairs (sr,gx) of 64, then the 36-pair diagonal).
// A ~150-block instantaneous window then touches ~8 B-tiles + ~24 A-tiles
// (~4 MB, L2-fit) instead of the full bx range (~8 MB, thrash).
__global__ __launch_bounds__(256, 4) void knn_kernel(const ushort* __restrict__ Xb,
                                                     const float* __restrict__ sqb,
                                                     uint* __restrict__ cand) {
  const int p = blockIdx.x;
  const int W = (p & 7) * CPX + (p >> 3);  // XCD chunking (2080 % 8 == 0)

  // decode W -> (bx, by), group-pair order
  int sr = 0, cum = 0;
#pragma unroll
  for (int s_ = 0; s_ < 7; ++s_) {  // cnt(sr) = 64*sr + 36
    const int c_ = 64 * s_ + 36;
    const int adv = (W >= cum + c_) ? 1 : 0;
    cum += adv * c_;
    sr += adv;
  }
  const int r = W - cum;
  int bx, by;
  if (r < 64 * sr) {  // off-diagonal group-pair (sr, gx)
    const int gx = r >> 6;
    const int q8 = r & 63;
    bx = gx * 8 + (q8 & 7);
    by = sr * 8 + (q8 >> 3);
  } else {  // diagonal group-pair: triangular decode within 8
    int t_ = r - 64 * sr;
    int u = 0;
#pragma unroll
    for (int s_ = 0; s_ < 7; ++s_) {
      const int adv = (t_ >= (u + 1) * (u + 2) / 2) ? 1 : 0;
      u += adv;
    }
    bx = sr * 8 + (t_ - u * (u + 1) / 2);
    by = sr * 8 + u;
  }

  __shared__ ushort As[2][BT][BK];  // 16 KB
  __shared__ ushort Bs[2][BT][BK];  // 16 KB

  const int i0 = bx * BT;
  const int j0 = by * BT;
  const int tid = threadIdx.x;
  const int lane = tid & 63;
  const int wave = tid >> 6;
  const int wr = wave >> 1, wc = wave & 1;
  const int q = lane >> 4, cr = lane & 15;

  const int srow = tid >> 2, sg = tid & 3;
  const int scsw = (sg ^ ((srow >> 1) & 3)) * 8;
  const size_t aoff0 = (size_t)(i0 + srow) * D + scsw;
  const size_t aoff1 = (size_t)(i0 + 64 + srow) * D + scsw;
  const size_t boff0 = (size_t)(j0 + srow) * D + scsw;
  const size_t boff1 = (size_t)(j0 + 64 + srow) * D + scsw;

  const int fcol = (q ^ ((cr >> 1) & 3)) * 8;

  auto STAGE = [&](int tt) {
    const int bf = tt & 1;
    const int ko = (tt & 15) * BK;
    gld16(Xb + aoff0 + ko, &As[bf][srow][sg * 8]);
    gld16(Xb + aoff1 + ko, &As[bf][64 + srow][sg * 8]);
    gld16(Xb + boff0 + ko, &Bs[bf][srow][sg * 8]);
    gld16(Xb + boff1 + ko, &Bs[bf][64 + srow][sg * 8]);
  };

  f32x4 acc[4][4];  // [n][m]: n = j-group, m = i-group
#pragma unroll
  for (int n = 0; n < 4; ++n)
#pragma unroll
    for (int m = 0; m < 4; ++m) acc[n][m] = (f32x4){0.f, 0.f, 0.f, 0.f};

  STAGE(0);

#pragma unroll 1
  for (int t = 0; t < NT; ++t) {
    const int buf = t & 1;
    WAITV0;
    BAR;
    STAGE((t + 1) & (NT - 1));

    const ushort(*Ab)[BK] = As[buf];
    const ushort(*Bb)[BK] = Bs[buf];
    short8v a[4], b[4];
#pragma unroll
    for (int m = 0; m < 4; ++m)
      a[m] = *(const short8v*)&Ab[wr * 64 + m * 16 + cr][fcol];
#pragma unroll
    for (int n = 0; n < 4; ++n)
      b[n] = *(const short8v*)&Bb[wc * 64 + n * 16 + cr][fcol];
    __builtin_amdgcn_s_setprio(1);
#pragma unroll
    for (int n = 0; n < 4; ++n)
#pragma unroll
      for (int m = 0; m < 4; ++m)
        acc[n][m] = __builtin_amdgcn_mfma_f32_16x16x32_bf16(b[n], a[m], acc[n][m], 0, 0, 0);
    __builtin_amdgcn_s_setprio(0);
  }

  // ---- i-side selection: rows i = i0+wr*64+m*16+cr, cands j in by-block ----
  float sjv[4][4];
#pragma unroll
  for (int n = 0; n < 4; ++n) {
    const float4 tt = *(const float4*)&sqb[j0 + wc * 64 + n * 16 + q * 4];
    sjv[n][0] = tt.x; sjv[n][1] = tt.y; sjv[n][2] = tt.z; sjv[n][3] = tt.w;
  }
#pragma unroll
  for (int m = 0; m < 4; ++m) {
    uint A0 = 0xFFFFFFFFu, A1 = 0xFFFFFFFFu;
#pragma unroll
    for (int n = 0; n < 4; ++n)
#pragma unroll
      for (int s = 0; s < 4; ++s) {
        const float f = fmaf(-2.f, acc[n][m][s], sjv[n][s]);  // > 0 by bias
        const uint pk = (__float_as_uint(f) & 0xFFFFFF80u) |
                        (uint)(wc * 64 + n * 16 + q * 4 + s);
        INS2(A0, A1, pk);
      }
    // exact top-2 of the wave's 64-j band: merge q-lanes (xor16, xor32)
    uint t0 = __shfl_xor(A0, 16), t1 = __shfl_xor(A1, 16);
    INS2(A0, A1, t0); INS2(A0, A1, t1);
    t0 = __shfl_xor(A0, 32); t1 = __shfl_xor(A1, 32);
    INS2(A0, A1, t0); INS2(A0, A1, t1);
    if (q == 0) {
      uint2 v; v.x = A0; v.y = A1;
      *(uint2*)&cand[(size_t)(i0 + wr * 64 + m * 16 + cr) * 256 + by * 4 + wc * 2] = v;
    }
  }

  // ---- j-side selection (off-diag only): rows j, cands i in bx-block ----
  if (bx != by) {
    float siv[4];
#pragma unroll
    for (int m = 0; m < 4; ++m) siv[m] = sqb[i0 + wr * 64 + m * 16 + cr];
#pragma unroll
    for (int n = 0; n < 4; ++n)
#pragma unroll
      for (int s = 0; s < 4; ++s) {
        uint B0 = 0xFFFFFFFFu, B1 = 0xFFFFFFFFu;
#pragma unroll
        for (int m = 0; m < 4; ++m) {
          const float f = fmaf(-2.f, acc[n][m][s], siv[m]);
          const uint pk = (__float_as_uint(f) & 0xFFFFFF80u) |
                          (uint)(wr * 64 + m * 16 + cr);
          INS2(B0, B1, pk);
        }
        // exact top-2 of the wr-half (64 i): merge across cr (xor 1,2,4,8)
#pragma unroll
        for (int off = 1; off <= 8; off <<= 1) {
          const uint u0 = __shfl_xor(B0, off), u1 = __shfl_xor(B1, off);
          INS2(B0, B1, u0); INS2(B0, B1, u1);
        }
        if ((lane & 15) == 0) {
          uint2 v; v.x = B0; v.y = B1;
          *(uint2*)&cand[(size_t)(j0 + wc * 64 + n * 16 + q * 4 + s) * 256 +
                         bx * 4 + wr * 2] = v;
        }
      }
  }
}

// ---------------- kernel 2: direct top-10 merge, bf16 Gram, solve, loss ----------------
__global__ __launch_bounds__(256) void lle_loss_kernel(
    const ushort* __restrict__ Xb, const float* __restrict__ Z,
    const uint* __restrict__ cand, float* __restrict__ rowsse) {
  const int lane = threadIdx.x & 63;
  const int i = blockIdx.x * 4 + (threadIdx.x >> 6);

  // 256 entries = [64 blk][4]; lane's uint4 = blk==lane's 4 entries.
  const uint4v pk4 = *(const uint4v*)&cand[(size_t)i * 256 + lane * 4];
  unsigned long long cvm[4];
#pragma unroll
  for (int kk = 0; kk < 4; ++kk) {
    const int g = lane * BT + (int)(pk4[kk] & 0x7Fu);
    const unsigned long long kv =
        ((unsigned long long)(pk4[kk] >> 7) << 13) | (unsigned long long)g;
    cvm[kk] = (g == i) ? ~0ull : kv;  // self-exclusion
  }

  int nbrj[KNN];
#pragma unroll
  for (int k = 0; k < KNN; ++k) {
    const unsigned long long m01 = cvm[0] < cvm[1] ? cvm[0] : cvm[1];
    const unsigned long long m23 = cvm[2] < cvm[3] ? cvm[2] : cvm[3];
    unsigned long long mn = m01 < m23 ? m01 : m23;
#pragma unroll
    for (int off = 32; off; off >>= 1) {
      const unsigned long long o = __shfl_xor(mn, off);
      mn = o < mn ? o : mn;
    }
    nbrj[k] = (int)(mn & 0x1FFFull);
#pragma unroll
    for (int kk = 0; kk < 4; ++kk)
      cvm[kk] = (cvm[kk] == mn) ? ~0ull : cvm[kk];  // u64 values unique
  }

  float xi[8];
  {
    const short8v v = *(const short8v*)&Xb[(size_t)i * D + lane * 8];
#pragma unroll
    for (int c = 0; c < 8; ++c) xi[c] = b2f((ushort)v[c]);
  }

  float df[KNN][8];
#pragma unroll
  for (int k = 0; k < KNN; ++k) {
    const int j = nbrj[k];
    const short8v v = *(const short8v*)&Xb[(size_t)j * D + lane * 8];
#pragma unroll
    for (int c = 0; c < 8; ++c) df[k][c] = b2f((ushort)v[c]) - xi[c];
  }

  float C[KNN][KNN];
#pragma unroll
  for (int k = 0; k < KNN; ++k) {
#pragma unroll
    for (int l = 0; l <= k; ++l) {
      float p = 0.f;
#pragma unroll
      for (int c = 0; c < 8; ++c) p = fmaf(df[k][c], df[l][c], p);
#pragma unroll
      for (int off = 32; off; off >>= 1) p += __shfl_xor(p, off);
      C[k][l] = p;
    }
  }

  float dinv[KNN];
#pragma unroll
  for (int j = 0; j < KNN; ++j) {
    float s = C[j][j] + REGC;
#pragma unroll
    for (int t = 0; t < KNN; ++t)
      if (t < j) s -= C[j][t] * C[j][t];
    const float dj = sqrtf(s);
    const float inv = 1.f / dj;
    dinv[j] = inv;
#pragma unroll
    for (int r2 = 0; r2 < KNN; ++r2) {
      if (r2 > j) {
        float s2 = C[r2][j];
#pragma unroll
        for (int t = 0; t < KNN; ++t)
          if (t < j) s2 -= C[r2][t] * C[j][t];
        C[r2][j] = s2 * inv;
      }
    }
  }
  float y[KNN], w[KNN];
#pragma unroll
  for (int r2 = 0; r2 < KNN; ++r2) {  // L y = 1
    float s = 1.f;
#pragma unroll
    for (int t = 0; t < KNN; ++t)
      if (t < r2) s -= C[r2][t] * y[t];
    y[r2] = s * dinv[r2];
  }
#pragma unroll
  for (int r2 = KNN - 1; r2 >= 0; --r2) {  // L^T w = y
    float s2 = y[r2];
#pragma unroll
    for (int t = 0; t < KNN; ++t)
      if (t > r2) s2 -= C[t][r2] * w[t];
    w[r2] = s2 * dinv[r2];
  }
  float ws = 0.f;
#pragma unroll
  for (int k = 0; k < KNN; ++k) ws += w[k];
  const float winv = 1.f / ws;

  float zr = 0.f;
#pragma unroll
  for (int k = 0; k < KNN; ++k)
    zr = fmaf(w[k] * winv, Z[(size_t)nbrj[k] * DZ + lane], zr);
  const float e = zr - Z[(size_t)i * DZ + lane];
  float se = e * e;
#pragma unroll
  for (int off = 32; off; off >>= 1) se += __shfl_xor(se, off);
  if (lane == 0) rowsse[i] = se;
}

// ---------------- kernel 3: single-block final reduction ----------------
__global__ __launch_bounds__(256) void reduce_kernel(const float* __restrict__ rowsse,
                                                     float* __restrict__ out) {
  const int tid = threadIdx.x;
  float s = 0.f;
#pragma unroll
  for (int c = 0; c < N / 256; ++c) s += rowsse[c * 256 + tid];
#pragma unroll
  for (int off = 32; off; off >>= 1) s += __shfl_xor(s, off);
  __shared__ float part[4];
  if ((tid & 63) == 0) part[tid >> 6] = s;
  __syncthreads();
  if (tid == 0)
    out[0] = (part[0] + part[1] + part[2] + part[3]) * (1.f / ((float)N * DZ));
}

// ---------------- launch ----------------
extern "C" void kernel_launch(void* const* d_in, const int* in_sizes, int n_in,
                              void* d_out, int out_size, void* d_ws, size_t ws_size,
                              hipStream_t stream) {
  const float* X = (const float*)d_in[0];
  const float* Z = (const float*)d_in[1];
  float* out = (float*)d_out;

  char* ws = (char*)d_ws;
  float* sqb = (float*)ws;                                   // 32 KB
  float* rowsse = (float*)(ws + 32 * 1024);                  // 32 KB
  ushort* Xb = (ushort*)(ws + 64 * 1024);                    // 8 MB
  uint* cand = (uint*)(ws + 64 * 1024 + (size_t)N * D * 2);  // 8 MB

  prep_kernel<<<N, 64, 0, stream>>>(X, sqb, Xb);
  knn_kernel<<<NPAIR, 256, 0, stream>>>(Xb, sqb, cand);
  lle_loss_kernel<<<N / 4, 256, 0, stream>>>(Xb, Z, cand, rowsse);
  reduce_kernel<<<1, 256, 0, stream>>>(rowsse, out);
}